// Round 1
// baseline (1148.830 us; speedup 1.0000x reference)
//
#include <hip/hip_runtime.h>
#include <hip/hip_fp16.h>

#define B_ 64
#define T_ 512
#define I_ 128
#define H_ 512

typedef _Float16 half2v __attribute__((ext_vector_type(2)));

__device__ __forceinline__ float dot2(unsigned a, unsigned b, float c) {
    return __builtin_amdgcn_fdot2(__builtin_bit_cast(half2v, a),
                                  __builtin_bit_cast(half2v, b), c, false);
}

// ---------------------------------------------------------------------------
// Kernel 1: convert W_hid (fp32 [H,H]) into packed f16 pairs, two layouts:
//  - regW  [kp][h] for kp in [0,192)  : per-thread register-resident part
//  - ldsW  [(j*H + h)*4 + m] for j in [0,16), m in [0,4) (kp = 192 + 4j + m)
//    so that in the dot loop, lane t does ds_read_b128 at uint4 index j*H+t
//    (lane-consecutive 16B lines -> conflict-free b128)
// ---------------------------------------------------------------------------
__global__ void wconv(const float* __restrict__ Whid,
                      unsigned* __restrict__ regW,
                      unsigned* __restrict__ ldsWsrc) {
    int p = blockIdx.x * 256 + threadIdx.x;   // 0 .. 131071 = H*256 pairs
    int kp = p & 255;
    int h  = p >> 8;
    float w0 = Whid[h * H_ + 2 * kp];
    float w1 = Whid[h * H_ + 2 * kp + 1];
    half2v hw = { (_Float16)w0, (_Float16)w1 };
    unsigned u = __builtin_bit_cast(unsigned, hw);
    if (kp < 192) {
        regW[kp * H_ + h] = u;
    } else {
        int q = kp - 192;
        int j = q >> 2, m = q & 3;
        ldsWsrc[(j * H_ + h) * 4 + m] = u;
    }
}

// ---------------------------------------------------------------------------
// Kernel 2: v_in[b,t,h] = sum_i x[b,t,i]*W_in[h,i] + b_in[h]
// GEMM [BT=32768,128] x [512,128]^T, fp32, 64x64 tile, K=128 staged in LDS.
// ---------------------------------------------------------------------------
__global__ __launch_bounds__(256) void vin_gemm(const float* __restrict__ x,
                                                const float* __restrict__ Win,
                                                const float* __restrict__ bin,
                                                float* __restrict__ vin) {
    __shared__ float xs[64][129];   // +1 pad breaks bank conflicts
    __shared__ float wsh[64][129];
    const int tid = threadIdx.x;
    const int m0 = blockIdx.x * 64;
    const int n0 = blockIdx.y * 64;

    // Stage tiles: 64 rows x 128 cols each, as float4 (8 per thread per tile)
    #pragma unroll
    for (int r = 0; r < 8; ++r) {
        int gi = r * 256 + tid;          // float4 index, 0..2047
        int row = gi >> 5;
        int c4 = (gi & 31) * 4;
        float4 v = ((const float4*)(x + (size_t)(m0 + row) * I_))[gi & 31];
        xs[row][c4] = v.x; xs[row][c4 + 1] = v.y;
        xs[row][c4 + 2] = v.z; xs[row][c4 + 3] = v.w;
        float4 w = ((const float4*)(Win + (size_t)(n0 + row) * I_))[gi & 31];
        wsh[row][c4] = w.x; wsh[row][c4 + 1] = w.y;
        wsh[row][c4 + 2] = w.z; wsh[row][c4 + 3] = w.w;
    }
    __syncthreads();

    const int ty = tid >> 4, tx = tid & 15;
    float acc[4][4] = {};
    #pragma unroll 4
    for (int k = 0; k < 128; ++k) {
        float a[4], bb[4];
        #pragma unroll
        for (int i = 0; i < 4; ++i) a[i] = xs[ty * 4 + i][k];
        #pragma unroll
        for (int j = 0; j < 4; ++j) bb[j] = wsh[tx * 4 + j][k];
        #pragma unroll
        for (int i = 0; i < 4; ++i)
            #pragma unroll
            for (int j = 0; j < 4; ++j)
                acc[i][j] = fmaf(a[i], bb[j], acc[i][j]);
    }

    float4 bv = ((const float4*)(bin + n0))[tx];
    #pragma unroll
    for (int i = 0; i < 4; ++i) {
        int m = m0 + ty * 4 + i;
        float4 o;
        o.x = acc[i][0] + bv.x; o.y = acc[i][1] + bv.y;
        o.z = acc[i][2] + bv.z; o.w = acc[i][3] + bv.w;
        ((float4*)(vin + (size_t)m * H_ + n0))[tx] = o;
    }
}

// ---------------------------------------------------------------------------
// Kernel 3: the sequential recurrence. One block per batch element.
// 512 threads; thread t owns hidden unit h=t. W row f16: 192 pairs in VGPRs,
// 64 pairs in LDS. fr (f16 pairs) double-buffered in LDS; broadcast reads.
// ---------------------------------------------------------------------------
__global__ __launch_bounds__(512, 2) void recurrent(
        const unsigned* __restrict__ regWg,
        const unsigned* __restrict__ ldsWsrc,
        const float* __restrict__ vin,
        const float* __restrict__ init_state,
        const float* __restrict__ b_hid,
        const float* __restrict__ alpha,
        float* __restrict__ out0,
        float* __restrict__ out1) {
    __shared__ unsigned ldsW[16 * H_ * 4];     // 128 KB
    __shared__ unsigned frbuf[2][H_ / 2];      // 2 x 1 KB of f16 pairs

    const int t = threadIdx.x;    // h index
    const int b = blockIdx.x;

    // Register-resident W part: pairs kp=0..191 of row h=t
    unsigned wreg[192];
    #pragma unroll
    for (int i = 0; i < 192; ++i) wreg[i] = regWg[i * H_ + t];   // coalesced

    // LDS W part: linear copy, 64 dwords per thread
    #pragma unroll 8
    for (int i = 0; i < 64; ++i) ldsW[i * H_ + t] = ldsWsrc[i * H_ + t];

    float v = init_state[b * H_ + t];
    float fr0 = fmaxf(v, 0.0f);
    ((_Float16*)frbuf[0])[t] = (_Float16)fr0;

    const float bh = b_hid[t];
    const float al = alpha[t];
    const float om = 1.0f - al;

    const float* vinp = vin + (size_t)b * T_ * H_ + t;
    float* o0 = out0 + (size_t)b * T_ * H_ + t;
    float* o1 = out1 + (size_t)b * T_ * H_ + t;

    __syncthreads();

    for (int step = 0; step < T_; ++step) {
        const int par = step & 1;
        float vinv = vinp[(size_t)step * H_];       // issued early, used late
        const uint4* fb = (const uint4*)frbuf[par]; // wave-uniform base
        float acc = 0.0f;

        // pairs 0..191 against register W
        #pragma unroll
        for (int g = 0; g < 48; ++g) {
            uint4 f = fb[g];                        // broadcast ds_read_b128
            acc = dot2(f.x, wreg[4 * g + 0], acc);
            acc = dot2(f.y, wreg[4 * g + 1], acc);
            acc = dot2(f.z, wreg[4 * g + 2], acc);
            acc = dot2(f.w, wreg[4 * g + 3], acc);
        }
        // pairs 192..255 against LDS W
        #pragma unroll
        for (int j = 0; j < 16; ++j) {
            uint4 f = fb[48 + j];                   // broadcast
            uint4 w = ((const uint4*)ldsW)[j * H_ + t];  // lane-consecutive
            acc = dot2(f.x, w.x, acc);
            acc = dot2(f.y, w.y, acc);
            acc = dot2(f.z, w.z, acc);
            acc = dot2(f.w, w.w, acc);
        }

        float vhid = acc + bh;
        float vnew = om * v + al * (vhid + vinv);
        float vr   = om * vnew + al * vhid;
        v = vnew;
        float frn = fmaxf(vnew, 0.0f);
        float frr = fmaxf(vr, 0.0f);

        o0[(size_t)step * H_] = frn;
        o1[(size_t)step * H_] = frr;

        ((_Float16*)frbuf[par ^ 1])[t] = (_Float16)frn;
        __syncthreads();   // new fr visible; old buffer free for next write
    }
}

// ---------------------------------------------------------------------------
extern "C" void kernel_launch(void* const* d_in, const int* in_sizes, int n_in,
                              void* d_out, int out_size, void* d_ws, size_t ws_size,
                              hipStream_t stream) {
    const float* x          = (const float*)d_in[0];
    const float* init_state = (const float*)d_in[1];
    const float* W_in       = (const float*)d_in[2];
    const float* b_in       = (const float*)d_in[3];
    const float* W_hid      = (const float*)d_in[4];
    const float* b_hid      = (const float*)d_in[5];
    const float* alpha      = (const float*)d_in[6];

    float* out0 = (float*)d_out;
    float* out1 = out0 + (size_t)B_ * T_ * H_;

    char* ws = (char*)d_ws;
    float*    vin      = (float*)ws;                          // 67,108,864 B
    unsigned* regW     = (unsigned*)(ws + 67108864);          //    393,216 B
    unsigned* ldsWsrc  = (unsigned*)(ws + 67502080);          //    131,072 B

    hipLaunchKernelGGL(wconv, dim3(512), dim3(256), 0, stream,
                       W_hid, regW, ldsWsrc);
    hipLaunchKernelGGL(vin_gemm, dim3(512, 8), dim3(256), 0, stream,
                       x, W_in, b_in, vin);
    hipLaunchKernelGGL(recurrent, dim3(64), dim3(512), 0, stream,
                       regW, ldsWsrc, vin, init_state, b_hid, alpha, out0, out1);
}